// Round 6
// baseline (687.641 us; speedup 1.0000x reference)
//
#include <hip/hip_runtime.h>
#include <hip/hip_bf16.h>

#define BB 8
#define LL 1024
#define DD 512
#define NH 8
#define DH 64
#define CO 7
#define GK 64          // K for corr GEMM: f=1..32, (re,im) pairs; f=0 dropped (softmax-invariant)
#define MM 8192        // NH*LL, Wt row length (m dim)

typedef __hip_bfloat16 bf16;
typedef __attribute__((ext_vector_type(8))) short short8;
typedef __attribute__((ext_vector_type(4))) float floatx4;
typedef __attribute__((ext_vector_type(4))) unsigned short ushort4v;

__device__ __forceinline__ float b2f(bf16 v){ return __bfloat162float(v); }
__device__ __forceinline__ bf16 f2b(float v){ return __float2bfloat16(v); }
__device__ __forceinline__ unsigned short f2bu(float v){
    bf16 h = f2b(v); return *(unsigned short*)&h;
}

// Decide whether global float data is genuine f32 (flag=1) or packed bf16 (flag=0).
__global__ void sniff_kernel(const unsigned* __restrict__ x, int* __restrict__ flag){
    unsigned u = x[threadIdx.x];
    int e = (u >> 23) & 0xff;
    int sane = (e >= 32 && e <= 200) ? 1 : 0;
    unsigned long long m = __ballot(sane);
    if(threadIdx.x == 0) *flag = (__popcll(m) >= 32) ? 1 : 0;
}

// moving average over the 7-channel input: xm = MA25(x), xs = x - xm  (f32 out)
__global__ __launch_bounds__(256) void ma7_kernel(const void* __restrict__ xv,
                                                  const int* __restrict__ flag,
                                                  float* __restrict__ xs,
                                                  float* __restrict__ xm){
    int idx = blockIdx.x*256 + threadIdx.x;
    if(idx >= BB*LL*7) return;
    bool f32 = (*flag != 0);
    int i = idx % 7;
    int row = idx / 7;
    int l = row & (LL-1);
    int b = row >> 10;
    int lo = l-12; if(lo<0) lo=0;
    int hi = l+12; if(hi>LL-1) hi=LL-1;
    float s = 0.f, xc;
    if(f32){
        const float* x = (const float*)xv + ((size_t)b*LL)*7 + i;
        for(int m=lo;m<=hi;m++) s += x[(size_t)m*7];
        xc = x[(size_t)l*7];
    }else{
        const bf16* x = (const bf16*)xv + ((size_t)b*LL)*7 + i;
        for(int m=lo;m<=hi;m++) s += b2f(x[(size_t)m*7]);
        xc = b2f(x[(size_t)l*7]);
    }
    float ma = s*(1.f/25.f);
    xm[idx] = ma;
    xs[idx] = xc - ma;
}

// seas[b,l,d] = xs@W + bias*(1-cnt/25); trend = xm@W + bias*cnt/25 (+= if accumulate)
__global__ __launch_bounds__(256) void embed2_kernel(const float* __restrict__ xs,
                                                     const float* __restrict__ xm,
                                                     const void* __restrict__ wv,
                                                     const void* __restrict__ bv,
                                                     const int* __restrict__ flag,
                                                     bf16* __restrict__ seas,
                                                     bf16* __restrict__ trend,
                                                     int accumulate){
    bool f32 = (*flag != 0);
    int idx = blockIdx.x*256 + threadIdx.x;
    int d = idx & (DD-1);
    int row = idx >> 9;
    int l = row & (LL-1);
    int lo = l-12; if(lo<0) lo=0;
    int hi = l+12; if(hi>LL-1) hi=LL-1;
    float cf = (float)(hi-lo+1) * (1.f/25.f);
    float wcol[7], bias;
    if(f32){
        const float* w = (const float*)wv;
        #pragma unroll
        for(int i=0;i<7;i++) wcol[i] = w[i*DD + d];
        bias = ((const float*)bv)[d];
    }else{
        const bf16* w = (const bf16*)wv;
        #pragma unroll
        for(int i=0;i<7;i++) wcol[i] = b2f(w[i*DD + d]);
        bias = b2f(((const bf16*)bv)[d]);
    }
    float sa = 0.f, ta = 0.f;
    #pragma unroll
    for(int i=0;i<7;i++){
        sa += xs[row*7+i]*wcol[i];
        ta += xm[row*7+i]*wcol[i];
    }
    seas[idx] = f2b(sa + bias*(1.f-cf));
    float t = ta + bias*cf;
    if(accumulate) t += b2f(trend[idx]);
    trend[idx] = f2b(t);
}

// trig table Tg[t][k]: k=2(f-1) -> cos(2*pi*f*t/1024), k=2(f-1)+1 -> sin, f=1..32
__global__ __launch_bounds__(64) void trig_init(bf16* __restrict__ Tg){
    int t = blockIdx.x, k = threadIdx.x;
    int f = (k >> 1) + 1;
    int ph = (f*t) & 1023;
    float s, c;
    __sincosf((float)ph * (6.28318530717958647692f/1024.f), &s, &c);
    Tg[(size_t)t*GK + k] = f2b((k & 1) ? s : c);
}

// Per (b,l): 64-pt DFT per head of q-row and k-row, C_f = qf*conj(kf), f=1..32;
// subtract cross-head mean; A[m=h*1024+l][2(f-1)]=Re*s, [2(f-1)+1]=-Im*s.
__global__ __launch_bounds__(256) void dft_kernel(const bf16* __restrict__ q,
                                                  const bf16* __restrict__ k,
                                                  bf16* __restrict__ Ab,
                                                  int b_off){
    __shared__ float qr[DD], kr[DD];
    __shared__ float mre[NH][32], mim[NH][32];
    int tid = threadIdx.x;
    int bloc = blockIdx.x >> 10;
    int b = b_off + bloc;
    int l = blockIdx.x & (LL-1);
    const bf16* qrow = q + ((size_t)b*LL + l)*DD;
    const bf16* krow = k + ((size_t)b*LL + l)*DD;
    qr[tid] = b2f(qrow[tid]); qr[tid+256] = b2f(qrow[tid+256]);
    kr[tid] = b2f(krow[tid]); kr[tid+256] = b2f(krow[tid+256]);
    __syncthreads();
    int h = tid >> 5, fi = tid & 31, f = fi + 1;
    const float* qh = qr + h*DH;
    const float* kh = kr + h*DH;
    float sb, cb;
    __sincosf((float)f * (6.28318530717958647692f/64.f), &sb, &cb);
    float cr = 1.f, ci = 0.f;
    float qre=0.f,qim=0.f,kre=0.f,kim=0.f;
    for(int j=0;j<DH;j++){
        float qv = qh[j], kv = kh[j];
        qre += qv*cr; qim += qv*ci;
        kre += kv*cr; kim += kv*ci;
        float nr = cr*cb + ci*sb;
        float ni = ci*cb - cr*sb;
        cr = nr; ci = ni;
    }
    const float scale = 1.f/512.f;
    float re = (qre*kre + qim*kim)*scale;
    float im = -(qim*kre - qre*kim)*scale;
    mre[h][fi] = re; mim[h][fi] = im;
    __syncthreads();
    float sre = 0.f, sim = 0.f;
    #pragma unroll
    for(int hh=0; hh<NH; hh++){ sre += mre[hh][fi]; sim += mim[hh][fi]; }
    re -= sre*0.125f; im -= sim*0.125f;
    size_t rowb = ((size_t)bloc*(NH*LL) + h*LL + l)*GK;
    Ab[rowb + 2*fi]   = f2b(re);
    Ab[rowb + 2*fi+1] = f2b(im);
}

// Fused corr GEMM + softmax -> TRANSPOSED W: Wt[bloc][t][m] (row len MM=8192).
// Block: 16 m-rows x 1024 t, K=64. C/D layout gives each lane 4 consecutive m
// at one t -> lane-local 8B packed store into Wt.
__global__ __launch_bounds__(256) void corr_softmax(const bf16* __restrict__ Ab,
                                                    const bf16* __restrict__ Tg,
                                                    bf16* __restrict__ Wt){
    __shared__ float redmx[4][16];
    __shared__ float redsm[4][16];
    int tid = threadIdx.x, wv = tid >> 6, lane = tid & 63;
    int m0 = blockIdx.x * 16;
    int bloc = blockIdx.y;
    int rr = lane & 15, kb = (lane>>4)*8;
    int rg = (lane>>4)*4;
    int t0 = wv*256;
    const short* Abase = (const short*)(Ab + ((size_t)bloc*MM)*GK);
    const short* Tb = (const short*)Tg;
    short8 af0 = *(const short8*)&Abase[(size_t)(m0+rr)*GK + kb];
    short8 af1 = *(const short8*)&Abase[(size_t)(m0+rr)*GK + 32 + kb];
    floatx4 acc[16];
    #pragma unroll
    for(int nt=0;nt<16;nt++){
        short8 b0 = *(const short8*)&Tb[(size_t)(t0+nt*16+rr)*GK + kb];
        short8 b1 = *(const short8*)&Tb[(size_t)(t0+nt*16+rr)*GK + 32 + kb];
        floatx4 a = {};
        a = __builtin_amdgcn_mfma_f32_16x16x32_bf16(af0, b0, a, 0,0,0);
        a = __builtin_amdgcn_mfma_f32_16x16x32_bf16(af1, b1, a, 0,0,0);
        acc[nt] = a;
    }
    float mx[4] = {-1e30f,-1e30f,-1e30f,-1e30f};
    #pragma unroll
    for(int nt=0;nt<16;nt++)
        #pragma unroll
        for(int r=0;r<4;r++) mx[r] = fmaxf(mx[r], acc[nt][r]);
    #pragma unroll
    for(int o=1;o<16;o<<=1)
        #pragma unroll
        for(int r=0;r<4;r++) mx[r] = fmaxf(mx[r], __shfl_xor(mx[r], o, 16));
    if(rr == 0){
        #pragma unroll
        for(int r=0;r<4;r++) redmx[wv][rg+r] = mx[r];
    }
    __syncthreads();
    #pragma unroll
    for(int r=0;r<4;r++)
        mx[r] = fmaxf(fmaxf(redmx[0][rg+r], redmx[1][rg+r]),
                      fmaxf(redmx[2][rg+r], redmx[3][rg+r]));
    float sm[4] = {};
    #pragma unroll
    for(int nt=0;nt<16;nt++)
        #pragma unroll
        for(int r=0;r<4;r++){
            float e = __expf(acc[nt][r] - mx[r]);
            acc[nt][r] = e; sm[r] += e;
        }
    #pragma unroll
    for(int o=1;o<16;o<<=1)
        #pragma unroll
        for(int r=0;r<4;r++) sm[r] += __shfl_xor(sm[r], o, 16);
    if(rr == 0){
        #pragma unroll
        for(int r=0;r<4;r++) redsm[wv][rg+r] = sm[r];
    }
    __syncthreads();
    float inv[4];
    #pragma unroll
    for(int r=0;r<4;r++)
        inv[r] = 1.f/(redsm[0][rg+r]+redsm[1][rg+r]+redsm[2][rg+r]+redsm[3][rg+r]);
    bf16* wbase = Wt + (size_t)bloc*((size_t)LL*MM) + m0 + rg;
    #pragma unroll
    for(int nt=0;nt<16;nt++){
        int t = t0 + nt*16 + rr;
        ushort4v pk;
        pk.x = f2bu(acc[nt][0]*inv[0]);
        pk.y = f2bu(acc[nt][1]*inv[1]);
        pk.z = f2bu(acc[nt][2]*inv[2]);
        pk.w = f2bu(acc[nt][3]*inv[3]);
        *(ushort4v*)(wbase + (size_t)t*MM) = pk;
    }
}

// MFMA pass2 on transposed W: Out[i,c] = sum_j Wt[i][h*1024+j]*V[j,c] per (bloc,h).
// A-fragments read DIRECT from global (Wt rows are K-contiguous); only V staged in
// LDS. Output packed: 4 consecutive i per lane -> b64 stores. dst[b][c*8192+h*1024+i]
__global__ __launch_bounds__(256) void ac_pass2(const bf16* __restrict__ Wt,
                                                const bf16* __restrict__ v,
                                                bf16* __restrict__ dst,
                                                int b_off){
    __shared__ __align__(16) unsigned short Bs[64][66];   // [c][j]
    int tid = threadIdx.x;
    int it = blockIdx.x, h = blockIdx.y, bloc = blockIdx.z;
    int b = b_off + bloc;
    int i0 = it*128;
    const unsigned short* wbase = (const unsigned short*)(Wt + (size_t)bloc*((size_t)LL*MM) + h*LL);
    const unsigned short* vbase = (const unsigned short*)(v + (size_t)b*LL*DD + h*DH);
    int wv = tid>>6, lane = tid&63;
    int wm = (wv>>1)*64, wn = (wv&1)*32;
    int rr = lane & 15, kb = (lane>>4)*8;
    floatx4 acc[4][2] = {};
    int cv = tid & 63,  jqv = tid >> 6;
    for(int j0=0; j0<LL; j0+=64){
        #pragma unroll
        for(int p=0;p<4;p++){
            int jbase = (jqv + p*4)*4;
            unsigned short v0 = vbase[(size_t)(j0+jbase+0)*DD + cv];
            unsigned short v1 = vbase[(size_t)(j0+jbase+1)*DD + cv];
            unsigned short v2 = vbase[(size_t)(j0+jbase+2)*DD + cv];
            unsigned short v3 = vbase[(size_t)(j0+jbase+3)*DD + cv];
            unsigned* dp = (unsigned*)&Bs[cv][jbase];
            dp[0] = (unsigned)v0 | ((unsigned)v1 << 16);
            dp[1] = (unsigned)v2 | ((unsigned)v3 << 16);
        }
        __syncthreads();
        #pragma unroll
        for(int ks=0;ks<2;ks++){
            short8 fa[4];
            union { unsigned u[4]; short8 s; } fb[2];
            #pragma unroll
            for(int mt=0;mt<4;mt++)
                fa[mt] = *(const short8*)&wbase[(size_t)(i0+wm+mt*16+rr)*MM + j0 + ks*32 + kb];
            #pragma unroll
            for(int nt=0;nt<2;nt++){
                const unsigned* bp = (const unsigned*)&Bs[wn+nt*16+rr][ks*32+kb];
                fb[nt].u[0]=bp[0]; fb[nt].u[1]=bp[1]; fb[nt].u[2]=bp[2]; fb[nt].u[3]=bp[3];
            }
            #pragma unroll
            for(int mt=0;mt<4;mt++)
                #pragma unroll
                for(int nt=0;nt<2;nt++)
                    acc[mt][nt] = __builtin_amdgcn_mfma_f32_16x16x32_bf16(fa[mt], fb[nt].s, acc[mt][nt], 0,0,0);
        }
        __syncthreads();
    }
    bf16* db = dst + (size_t)b*LL*DD;
    int qrow = (lane>>4)*4, qcol = lane & 15;
    #pragma unroll
    for(int nt=0;nt<2;nt++){
        int c = wn + nt*16 + qcol;
        #pragma unroll
        for(int mt=0;mt<4;mt++){
            int ibase = i0 + wm + mt*16 + qrow;
            ushort4v pk;
            pk.x = f2bu(acc[mt][nt][0]);
            pk.y = f2bu(acc[mt][nt][1]);
            pk.z = f2bu(acc[mt][nt][2]);
            pk.w = f2bu(acc[mt][nt][3]);
            *(ushort4v*)(db + (size_t)c*MM + h*LL + ibase) = pk;
        }
    }
}

// out = (seas + trend_sum) @ proj_w + proj_b  (dtype per flag)
__global__ __launch_bounds__(64) void final_kernel(const bf16* __restrict__ s,
                                                   const bf16* __restrict__ t,
                                                   const void* __restrict__ pwv,
                                                   const void* __restrict__ pbv,
                                                   const int* __restrict__ flag,
                                                   void* __restrict__ outv){
    bool f32 = (*flag != 0);
    int row = blockIdx.x;
    int lane = threadIdx.x;
    const bf16* sr = s + (size_t)row*DD;
    const bf16* tr = t + (size_t)row*DD;
    float acc[CO] = {};
    for(int j=lane; j<DD; j+=64){
        float dv = b2f(sr[j]) + b2f(tr[j]);
        if(f32){
            const float* pw = (const float*)pwv;
            #pragma unroll
            for(int c=0;c<CO;c++) acc[c] += dv * pw[j*CO + c];
        }else{
            const bf16* pw = (const bf16*)pwv;
            #pragma unroll
            for(int c=0;c<CO;c++) acc[c] += dv * b2f(pw[j*CO + c]);
        }
    }
    #pragma unroll
    for(int c=0;c<CO;c++){
        float vsum = acc[c];
        for(int off=32;off;off>>=1) vsum += __shfl_down(vsum,off,64);
        if(lane==0){
            float bias = f32 ? ((const float*)pbv)[c] : b2f(((const bf16*)pbv)[c]);
            float o = vsum + bias;
            if(f32) ((float*)outv)[(size_t)row*CO + c] = o;
            else    ((bf16*)outv)[(size_t)row*CO + c] = f2b(o);
        }
    }
}

extern "C" void kernel_launch(void* const* d_in, const int* in_sizes, int n_in,
                              void* d_out, int out_size, void* d_ws, size_t ws_size,
                              hipStream_t stream){
    const void* x_enc  = d_in[0];
    const void* x_dec  = d_in[2];
    const void* enc_w  = d_in[4];
    const void* enc_b  = d_in[5];
    const void* dec_w  = d_in[6];
    const void* dec_b  = d_in[7];
    const void* proj_w = d_in[8];
    const void* proj_b = d_in[9];

    int*  flag = (int*)d_ws;
    const size_t NE = (size_t)BB*LL*DD;
    bf16* A  = (bf16*)((char*)d_ws + 1024);
    bf16* Bf = A  + NE;
    bf16* C  = Bf + NE;
    bf16* T  = C  + NE;
    bf16* Tg = T  + NE;
    float* xs = (float*)(Tg + (size_t)LL*GK);
    float* xm = xs + (size_t)BB*LL*7;
    bf16* Ab  = (bf16*)(xm + (size_t)BB*LL*7);

    const size_t AB_ELEMS = (size_t)MM*GK;
    const size_t W_ELEMS  = (size_t)LL*MM;
    size_t base = (size_t)((char*)Ab - (char*)d_ws);
    int bsz = 1;
    for(int cand : {8,4,2}){
        if(base + (size_t)cand*(AB_ELEMS + W_ELEMS)*sizeof(bf16) <= ws_size){ bsz = cand; break; }
    }
    bf16* W = Ab + (size_t)bsz*AB_ELEMS;

    sniff_kernel<<<1,64,0,stream>>>((const unsigned*)x_enc, flag);
    trig_init<<<LL,64,0,stream>>>(Tg);

    auto autocorr = [&](const bf16* q, const bf16* kv, bf16* dst){
        for(int b0 = 0; b0 < BB; b0 += bsz){
            dft_kernel<<<bsz*LL, 256, 0, stream>>>(q, kv, Ab, b0);
            corr_softmax<<<dim3(512, bsz), 256, 0, stream>>>(Ab, Tg, W);
            ac_pass2<<<dim3(8, NH, bsz), 256, 0, stream>>>(W, kv, dst, b0);
        }
    };

    const int MA_GRID = (BB*LL*7 + 255)/256;
    ma7_kernel<<<MA_GRID,256,0,stream>>>(x_enc, flag, xs, xm);
    embed2_kernel<<<16384,256,0,stream>>>(xs, xm, enc_w, enc_b, flag, A, T, 0);
    autocorr(A, A, Bf);      // layer 1 -> Bf
    autocorr(Bf, Bf, A);     // layer 2 -> A (= enc_seasonal out)

    ma7_kernel<<<MA_GRID,256,0,stream>>>(x_dec, flag, xs, xm);
    embed2_kernel<<<16384,256,0,stream>>>(xs, xm, dec_w, dec_b, flag, Bf, T, 1);
    autocorr(Bf, A, C);      // cross layer -> C

    final_kernel<<<BB*LL,64,0,stream>>>(C, T, proj_w, proj_b, flag, d_out);
}

// Round 7
// 682.790 us; speedup vs baseline: 1.0071x; 1.0071x over previous
//
#include <hip/hip_runtime.h>
#include <hip/hip_bf16.h>

#define BB 8
#define LL 1024
#define DD 512
#define NH 8
#define DH 64
#define CO 7
#define GK 64          // K for corr GEMM: f=1..32, (re,im) pairs; f=0 dropped (softmax-invariant)
#define MM 8192        // NH*LL rows per batch

typedef __hip_bfloat16 bf16;
typedef __attribute__((ext_vector_type(8))) short short8;
typedef __attribute__((ext_vector_type(4))) float floatx4;
typedef __attribute__((ext_vector_type(4))) unsigned short ushort4v;

__device__ __forceinline__ float b2f(bf16 v){ return __bfloat162float(v); }
__device__ __forceinline__ bf16 f2b(float v){ return __float2bfloat16(v); }
__device__ __forceinline__ unsigned short f2bu(float v){
    bf16 h = f2b(v); return *(unsigned short*)&h;
}

// Decide whether global float data is genuine f32 (flag=1) or packed bf16 (flag=0).
__global__ void sniff_kernel(const unsigned* __restrict__ x, int* __restrict__ flag){
    unsigned u = x[threadIdx.x];
    int e = (u >> 23) & 0xff;
    int sane = (e >= 32 && e <= 200) ? 1 : 0;
    unsigned long long m = __ballot(sane);
    if(threadIdx.x == 0) *flag = (__popcll(m) >= 32) ? 1 : 0;
}

// moving average over the 7-channel input: xm = MA25(x), xs = x - xm  (f32 out)
__global__ __launch_bounds__(256) void ma7_kernel(const void* __restrict__ xv,
                                                  const int* __restrict__ flag,
                                                  float* __restrict__ xs,
                                                  float* __restrict__ xm){
    int idx = blockIdx.x*256 + threadIdx.x;
    if(idx >= BB*LL*7) return;
    bool f32 = (*flag != 0);
    int i = idx % 7;
    int row = idx / 7;
    int l = row & (LL-1);
    int b = row >> 10;
    int lo = l-12; if(lo<0) lo=0;
    int hi = l+12; if(hi>LL-1) hi=LL-1;
    float s = 0.f, xc;
    if(f32){
        const float* x = (const float*)xv + ((size_t)b*LL)*7 + i;
        for(int m=lo;m<=hi;m++) s += x[(size_t)m*7];
        xc = x[(size_t)l*7];
    }else{
        const bf16* x = (const bf16*)xv + ((size_t)b*LL)*7 + i;
        for(int m=lo;m<=hi;m++) s += b2f(x[(size_t)m*7]);
        xc = b2f(x[(size_t)l*7]);
    }
    float ma = s*(1.f/25.f);
    xm[idx] = ma;
    xs[idx] = xc - ma;
}

// seas[b,l,d] = xs@W + bias*(1-cnt/25); trend = xm@W + bias*cnt/25 (+= if accumulate)
__global__ __launch_bounds__(256) void embed2_kernel(const float* __restrict__ xs,
                                                     const float* __restrict__ xm,
                                                     const void* __restrict__ wv,
                                                     const void* __restrict__ bv,
                                                     const int* __restrict__ flag,
                                                     bf16* __restrict__ seas,
                                                     bf16* __restrict__ trend,
                                                     int accumulate){
    bool f32 = (*flag != 0);
    int idx = blockIdx.x*256 + threadIdx.x;
    int d = idx & (DD-1);
    int row = idx >> 9;
    int l = row & (LL-1);
    int lo = l-12; if(lo<0) lo=0;
    int hi = l+12; if(hi>LL-1) hi=LL-1;
    float cf = (float)(hi-lo+1) * (1.f/25.f);
    float wcol[7], bias;
    if(f32){
        const float* w = (const float*)wv;
        #pragma unroll
        for(int i=0;i<7;i++) wcol[i] = w[i*DD + d];
        bias = ((const float*)bv)[d];
    }else{
        const bf16* w = (const bf16*)wv;
        #pragma unroll
        for(int i=0;i<7;i++) wcol[i] = b2f(w[i*DD + d]);
        bias = b2f(((const bf16*)bv)[d]);
    }
    float sa = 0.f, ta = 0.f;
    #pragma unroll
    for(int i=0;i<7;i++){
        sa += xs[row*7+i]*wcol[i];
        ta += xm[row*7+i]*wcol[i];
    }
    seas[idx] = f2b(sa + bias*(1.f-cf));
    float t = ta + bias*cf;
    if(accumulate) t += b2f(trend[idx]);
    trend[idx] = f2b(t);
}

// trig table Tg[t][k]: k=2(f-1) -> cos(2*pi*f*t/1024), k=2(f-1)+1 -> sin, f=1..32
__global__ __launch_bounds__(64) void trig_init(bf16* __restrict__ Tg){
    int t = blockIdx.x, k = threadIdx.x;
    int f = (k >> 1) + 1;
    int ph = (f*t) & 1023;
    float s, c;
    __sincosf((float)ph * (6.28318530717958647692f/1024.f), &s, &c);
    Tg[(size_t)t*GK + k] = f2b((k & 1) ? s : c);
}

// Per (b,l): 64-pt DFT per head of q-row and k-row, C_f = qf*conj(kf), f=1..32;
// subtract cross-head mean; A[m=h*1024+l][2(f-1)]=Re*s, [2(f-1)+1]=-Im*s.
__global__ __launch_bounds__(256) void dft_kernel(const bf16* __restrict__ q,
                                                  const bf16* __restrict__ k,
                                                  bf16* __restrict__ Ab){
    __shared__ float qr[DD], kr[DD];
    __shared__ float mre[NH][32], mim[NH][32];
    int tid = threadIdx.x;
    int bloc = blockIdx.x >> 10;
    int l = blockIdx.x & (LL-1);
    const bf16* qrow = q + ((size_t)bloc*LL + l)*DD;
    const bf16* krow = k + ((size_t)bloc*LL + l)*DD;
    qr[tid] = b2f(qrow[tid]); qr[tid+256] = b2f(qrow[tid+256]);
    kr[tid] = b2f(krow[tid]); kr[tid+256] = b2f(krow[tid+256]);
    __syncthreads();
    int h = tid >> 5, fi = tid & 31, f = fi + 1;
    const float* qh = qr + h*DH;
    const float* kh = kr + h*DH;
    float sb, cb;
    __sincosf((float)f * (6.28318530717958647692f/64.f), &sb, &cb);
    float cr = 1.f, ci = 0.f;
    float qre=0.f,qim=0.f,kre=0.f,kim=0.f;
    for(int j=0;j<DH;j++){
        float qv = qh[j], kv = kh[j];
        qre += qv*cr; qim += qv*ci;
        kre += kv*cr; kim += kv*ci;
        float nr = cr*cb + ci*sb;
        float ni = ci*cb - cr*sb;
        cr = nr; ci = ni;
    }
    const float scale = 1.f/512.f;
    float re = (qre*kre + qim*kim)*scale;
    float im = -(qim*kre - qre*kim)*scale;
    mre[h][fi] = re; mim[h][fi] = im;
    __syncthreads();
    float sre = 0.f, sim = 0.f;
    #pragma unroll
    for(int hh=0; hh<NH; hh++){ sre += mre[hh][fi]; sim += mim[hh][fi]; }
    re -= sre*0.125f; im -= sim*0.125f;
    size_t rowb = ((size_t)bloc*MM + h*LL + l)*GK;
    Ab[rowb + 2*fi]   = f2b(re);
    Ab[rowb + 2*fi+1] = f2b(im);
}

// Phase 1: per-row softmax stats. Block = 16 m-rows x 1024 t (4 waves x 256 t).
// Writes rs[bloc][m] = (rowmax, 1/rowsum). No W materialization.
__global__ __launch_bounds__(256) void rowstats_kernel(const bf16* __restrict__ Ab,
                                                       const bf16* __restrict__ Tg,
                                                       float2* __restrict__ rs){
    __shared__ float redmx[4][16];
    __shared__ float redsm[4][16];
    int tid = threadIdx.x, wv = tid >> 6, lane = tid & 63;
    int m0 = blockIdx.x * 16;
    int bloc = blockIdx.y;
    int rr = lane & 15, kb = (lane>>4)*8;
    int rg = (lane>>4)*4;
    int t0 = wv*256;
    const short* Abase = (const short*)(Ab + ((size_t)bloc*MM)*GK);
    const short* Tb = (const short*)Tg;
    short8 af0 = *(const short8*)&Abase[(size_t)(m0+rr)*GK + kb];
    short8 af1 = *(const short8*)&Abase[(size_t)(m0+rr)*GK + 32 + kb];
    floatx4 acc[16];
    #pragma unroll
    for(int nt=0;nt<16;nt++){
        short8 b0 = *(const short8*)&Tb[(size_t)(t0+nt*16+rr)*GK + kb];
        short8 b1 = *(const short8*)&Tb[(size_t)(t0+nt*16+rr)*GK + 32 + kb];
        floatx4 a = {};
        a = __builtin_amdgcn_mfma_f32_16x16x32_bf16(af0, b0, a, 0,0,0);
        a = __builtin_amdgcn_mfma_f32_16x16x32_bf16(af1, b1, a, 0,0,0);
        acc[nt] = a;
    }
    float mx[4] = {-1e30f,-1e30f,-1e30f,-1e30f};
    #pragma unroll
    for(int nt=0;nt<16;nt++)
        #pragma unroll
        for(int r=0;r<4;r++) mx[r] = fmaxf(mx[r], acc[nt][r]);
    #pragma unroll
    for(int o=1;o<16;o<<=1)
        #pragma unroll
        for(int r=0;r<4;r++) mx[r] = fmaxf(mx[r], __shfl_xor(mx[r], o, 16));
    if(rr == 0){
        #pragma unroll
        for(int r=0;r<4;r++) redmx[wv][rg+r] = mx[r];
    }
    __syncthreads();
    #pragma unroll
    for(int r=0;r<4;r++)
        mx[r] = fmaxf(fmaxf(redmx[0][rg+r], redmx[1][rg+r]),
                      fmaxf(redmx[2][rg+r], redmx[3][rg+r]));
    float sm[4] = {};
    #pragma unroll
    for(int nt=0;nt<16;nt++)
        #pragma unroll
        for(int r=0;r<4;r++) sm[r] += __expf(acc[nt][r] - mx[r]);
    #pragma unroll
    for(int o=1;o<16;o<<=1)
        #pragma unroll
        for(int r=0;r<4;r++) sm[r] += __shfl_xor(sm[r], o, 16);
    if(rr == 0){
        #pragma unroll
        for(int r=0;r<4;r++) redsm[wv][rg+r] = sm[r];
    }
    __syncthreads();
    if(tid < 16){
        float S = redsm[0][tid]+redsm[1][tid]+redsm[2][tid]+redsm[3][tid];
        float m = fmaxf(fmaxf(redmx[0][tid],redmx[1][tid]),
                        fmaxf(redmx[2][tid],redmx[3][tid]));
        rs[(size_t)bloc*MM + m0 + tid] = make_float2(m, 1.f/S);
    }
}

// Phase 2: fused corr-recompute + softmax + PV. Per (i-tile 128, h, bloc):
// loop j in chunks of 64: MFMA1 (a=Ab j-rows, b=Tg i-rows -> D[j][i], lane's 4
// regs j-contiguous), exp(.-mx_j)*invS_j, P -> LDS in A-operand layout, MFMA2
// P[i][j] x Vs[c][j]. Out[i,c] -> dst[b][c*8192 + h*1024 + i].
__global__ __launch_bounds__(256, 4) void fused_pv(const bf16* __restrict__ Ab,
                                                   const bf16* __restrict__ Tg,
                                                   const float2* __restrict__ rs,
                                                   const bf16* __restrict__ v,
                                                   bf16* __restrict__ dst){
    __shared__ __align__(16) unsigned short Pl[128][68];  // [i_loc][j_loc], pitch 68 (8B ops)
    __shared__ __align__(16) unsigned short Vs[64][68];   // [c][j_loc]
    __shared__ float2 st[LL];                             // (mx, invS) per j
    int tid = threadIdx.x, wv = tid >> 6, lane = tid & 63;
    int q = lane >> 4, n = lane & 15;
    int i0 = blockIdx.x * 128;
    int h = blockIdx.y, bloc = blockIdx.z;
    const short* Abase = (const short*)(Ab + ((size_t)bloc*MM + (size_t)h*LL)*GK);
    const short* Tb = (const short*)Tg;
    const float2* rsb = rs + (size_t)bloc*MM + (size_t)h*LL;
    const unsigned short* vbase = (const unsigned short*)(v + (size_t)bloc*LL*DD + h*DH);
    for(int s=tid; s<LL; s+=256) st[s] = rsb[s];
    short8 tgf[2][2];
    #pragma unroll
    for(int ti=0;ti<2;ti++)
        #pragma unroll
        for(int kc=0;kc<2;kc++)
            tgf[ti][kc] = *(const short8*)&Tb[(size_t)(i0 + wv*32 + ti*16 + n)*GK + kc*32 + q*8];
    int cv = tid & 63, jg = tid >> 6;
    floatx4 acc[2][4] = {};
    __syncthreads();
    for(int j0=0; j0<LL; j0+=64){
        // stage V chunk: Vs[c][j], packed j-pairs (coalesced 128B global rows)
        #pragma unroll
        for(int p=0;p<8;p++){
            int j = (jg*8+p)*2;
            unsigned short v0 = vbase[(size_t)(j0+j)*DD + cv];
            unsigned short v1 = vbase[(size_t)(j0+j+1)*DD + cv];
            *(unsigned*)&Vs[cv][j] = (unsigned)v0 | ((unsigned)v1 << 16);
        }
        // MFMA1 + exp + P write, per 16-row j group
        #pragma unroll
        for(int tj=0;tj<4;tj++){
            short8 a0 = *(const short8*)&Abase[(size_t)(j0+tj*16+n)*GK + q*8];
            short8 a1 = *(const short8*)&Abase[(size_t)(j0+tj*16+n)*GK + 32 + q*8];
            floatx4 d1[2];
            #pragma unroll
            for(int ti=0;ti<2;ti++){
                floatx4 d = {};
                d = __builtin_amdgcn_mfma_f32_16x16x32_bf16(a0, tgf[ti][0], d, 0,0,0);
                d = __builtin_amdgcn_mfma_f32_16x16x32_bf16(a1, tgf[ti][1], d, 0,0,0);
                d1[ti] = d;
            }
            float mxr[4], ivr[4];
            #pragma unroll
            for(int r=0;r<4;r++){
                float2 sr = st[j0 + tj*16 + q*4 + r];
                mxr[r] = sr.x; ivr[r] = sr.y;
            }
            #pragma unroll
            for(int ti=0;ti<2;ti++){
                ushort4v pk;
                pk.x = f2bu(__expf(d1[ti][0]-mxr[0])*ivr[0]);
                pk.y = f2bu(__expf(d1[ti][1]-mxr[1])*ivr[1]);
                pk.z = f2bu(__expf(d1[ti][2]-mxr[2])*ivr[2]);
                pk.w = f2bu(__expf(d1[ti][3]-mxr[3])*ivr[3]);
                *(ushort4v*)&Pl[wv*32 + ti*16 + n][tj*16 + q*4] = pk;
            }
        }
        __syncthreads();
        // MFMA2: Out[i][c] += P[i][j] * Vs[c][j]
        #pragma unroll
        for(int kc=0;kc<2;kc++){
            union { ushort4v h2[2]; short8 s; } a2[2], b2;
            #pragma unroll
            for(int ti=0;ti<2;ti++){
                const unsigned short* pp = &Pl[wv*32 + ti*16 + n][kc*32 + q*8];
                a2[ti].h2[0] = *(const ushort4v*)pp;
                a2[ti].h2[1] = *(const ushort4v*)(pp+4);
            }
            #pragma unroll
            for(int cs=0;cs<4;cs++){
                const unsigned short* vp = &Vs[cs*16 + n][kc*32 + q*8];
                b2.h2[0] = *(const ushort4v*)vp;
                b2.h2[1] = *(const ushort4v*)(vp+4);
                #pragma unroll
                for(int ti=0;ti<2;ti++)
                    acc[ti][cs] = __builtin_amdgcn_mfma_f32_16x16x32_bf16(a2[ti].s, b2.s, acc[ti][cs], 0,0,0);
            }
        }
        __syncthreads();
    }
    bf16* db = dst + (size_t)bloc*LL*DD;
    #pragma unroll
    for(int cs=0;cs<4;cs++){
        int c = cs*16 + n;
        #pragma unroll
        for(int ti=0;ti<2;ti++){
            int ib = i0 + wv*32 + ti*16 + q*4;
            ushort4v pk;
            pk.x = f2bu(acc[ti][cs][0]);
            pk.y = f2bu(acc[ti][cs][1]);
            pk.z = f2bu(acc[ti][cs][2]);
            pk.w = f2bu(acc[ti][cs][3]);
            *(ushort4v*)(db + (size_t)c*8192 + h*1024 + ib) = pk;
        }
    }
}

// out = (seas + trend_sum) @ proj_w + proj_b  (dtype per flag)
__global__ __launch_bounds__(64) void final_kernel(const bf16* __restrict__ s,
                                                   const bf16* __restrict__ t,
                                                   const void* __restrict__ pwv,
                                                   const void* __restrict__ pbv,
                                                   const int* __restrict__ flag,
                                                   void* __restrict__ outv){
    bool f32 = (*flag != 0);
    int row = blockIdx.x;
    int lane = threadIdx.x;
    const bf16* sr = s + (size_t)row*DD;
    const bf16* tr = t + (size_t)row*DD;
    float acc[CO] = {};
    for(int j=lane; j<DD; j+=64){
        float dv = b2f(sr[j]) + b2f(tr[j]);
        if(f32){
            const float* pw = (const float*)pwv;
            #pragma unroll
            for(int c=0;c<CO;c++) acc[c] += dv * pw[j*CO + c];
        }else{
            const bf16* pw = (const bf16*)pwv;
            #pragma unroll
            for(int c=0;c<CO;c++) acc[c] += dv * b2f(pw[j*CO + c]);
        }
    }
    #pragma unroll
    for(int c=0;c<CO;c++){
        float vsum = acc[c];
        for(int off=32;off;off>>=1) vsum += __shfl_down(vsum,off,64);
        if(lane==0){
            float bias = f32 ? ((const float*)pbv)[c] : b2f(((const bf16*)pbv)[c]);
            float o = vsum + bias;
            if(f32) ((float*)outv)[(size_t)row*CO + c] = o;
            else    ((bf16*)outv)[(size_t)row*CO + c] = f2b(o);
        }
    }
}

extern "C" void kernel_launch(void* const* d_in, const int* in_sizes, int n_in,
                              void* d_out, int out_size, void* d_ws, size_t ws_size,
                              hipStream_t stream){
    const void* x_enc  = d_in[0];
    const void* x_dec  = d_in[2];
    const void* enc_w  = d_in[4];
    const void* enc_b  = d_in[5];
    const void* dec_w  = d_in[6];
    const void* dec_b  = d_in[7];
    const void* proj_w = d_in[8];
    const void* proj_b = d_in[9];

    int*  flag = (int*)d_ws;
    const size_t NE = (size_t)BB*LL*DD;
    bf16* A  = (bf16*)((char*)d_ws + 1024);
    bf16* Bf = A  + NE;
    bf16* C  = Bf + NE;
    bf16* T  = C  + NE;
    bf16* Tg = T  + NE;
    float* xs = (float*)(Tg + (size_t)LL*GK);
    float* xm = xs + (size_t)BB*LL*7;
    bf16* Ab  = (bf16*)(xm + (size_t)BB*LL*7);          // [BB][MM][GK]
    float2* rs = (float2*)(Ab + (size_t)BB*MM*GK);      // [BB][MM]

    sniff_kernel<<<1,64,0,stream>>>((const unsigned*)x_enc, flag);
    trig_init<<<LL,64,0,stream>>>(Tg);

    auto autocorr = [&](const bf16* q, const bf16* kv, bf16* dst){
        dft_kernel<<<BB*LL, 256, 0, stream>>>(q, kv, Ab);
        rowstats_kernel<<<dim3(512, BB), 256, 0, stream>>>(Ab, Tg, rs);
        fused_pv<<<dim3(8, NH, BB), 256, 0, stream>>>(Ab, Tg, rs, kv, dst);
    };

    const int MA_GRID = (BB*LL*7 + 255)/256;
    ma7_kernel<<<MA_GRID,256,0,stream>>>(x_enc, flag, xs, xm);
    embed2_kernel<<<16384,256,0,stream>>>(xs, xm, enc_w, enc_b, flag, A, T, 0);
    autocorr(A, A, Bf);      // layer 1 -> Bf
    autocorr(Bf, Bf, A);     // layer 2 -> A (= enc_seasonal out)

    ma7_kernel<<<MA_GRID,256,0,stream>>>(x_dec, flag, xs, xm);
    embed2_kernel<<<16384,256,0,stream>>>(xs, xm, dec_w, dec_b, flag, Bf, T, 1);
    autocorr(Bf, A, C);      // cross layer -> C

    final_kernel<<<BB*LL,64,0,stream>>>(C, T, proj_w, proj_b, flag, d_out);
}

// Round 8
// 574.551 us; speedup vs baseline: 1.1968x; 1.1884x over previous
//
#include <hip/hip_runtime.h>
#include <hip/hip_bf16.h>

#define BB 8
#define LL 1024
#define DD 512
#define NH 8
#define DH 64
#define CO 7
#define GK 64          // K for corr GEMM: f=1..32, (re,im) pairs; f=0 dropped (softmax-invariant)
#define MM 8192        // NH*LL rows per batch

typedef __hip_bfloat16 bf16;
typedef __attribute__((ext_vector_type(8))) short short8;
typedef __attribute__((ext_vector_type(4))) float floatx4;
typedef __attribute__((ext_vector_type(4))) unsigned short ushort4v;

__device__ __forceinline__ float b2f(bf16 v){ return __bfloat162float(v); }
__device__ __forceinline__ bf16 f2b(float v){ return __float2bfloat16(v); }
__device__ __forceinline__ unsigned short f2bu(float v){
    bf16 h = f2b(v); return *(unsigned short*)&h;
}
__device__ __forceinline__ float bu2f(unsigned short u){
    union{unsigned i; float f;} x; x.i = ((unsigned)u)<<16; return x.f;
}

// Decide whether global float data is genuine f32 (flag=1) or packed bf16 (flag=0).
__global__ void sniff_kernel(const unsigned* __restrict__ x, int* __restrict__ flag){
    unsigned u = x[threadIdx.x];
    int e = (u >> 23) & 0xff;
    int sane = (e >= 32 && e <= 200) ? 1 : 0;
    unsigned long long m = __ballot(sane);
    if(threadIdx.x == 0) *flag = (__popcll(m) >= 32) ? 1 : 0;
}

// moving average over the 7-channel input: xm = MA25(x), xs = x - xm  (f32 out)
__global__ __launch_bounds__(256) void ma7_kernel(const void* __restrict__ xv,
                                                  const int* __restrict__ flag,
                                                  float* __restrict__ xs,
                                                  float* __restrict__ xm){
    int idx = blockIdx.x*256 + threadIdx.x;
    if(idx >= BB*LL*7) return;
    bool f32 = (*flag != 0);
    int i = idx % 7;
    int row = idx / 7;
    int l = row & (LL-1);
    int b = row >> 10;
    int lo = l-12; if(lo<0) lo=0;
    int hi = l+12; if(hi>LL-1) hi=LL-1;
    float s = 0.f, xc;
    if(f32){
        const float* x = (const float*)xv + ((size_t)b*LL)*7 + i;
        for(int m=lo;m<=hi;m++) s += x[(size_t)m*7];
        xc = x[(size_t)l*7];
    }else{
        const bf16* x = (const bf16*)xv + ((size_t)b*LL)*7 + i;
        for(int m=lo;m<=hi;m++) s += b2f(x[(size_t)m*7]);
        xc = b2f(x[(size_t)l*7]);
    }
    float ma = s*(1.f/25.f);
    xm[idx] = ma;
    xs[idx] = xc - ma;
}

// seas[b,l,d] = xs@W + bias*(1-cnt/25); trend = xm@W + bias*cnt/25 (+= if accumulate)
__global__ __launch_bounds__(256) void embed2_kernel(const float* __restrict__ xs,
                                                     const float* __restrict__ xm,
                                                     const void* __restrict__ wv,
                                                     const void* __restrict__ bv,
                                                     const int* __restrict__ flag,
                                                     bf16* __restrict__ seas,
                                                     bf16* __restrict__ trend,
                                                     int accumulate){
    bool f32 = (*flag != 0);
    int idx = blockIdx.x*256 + threadIdx.x;
    int d = idx & (DD-1);
    int row = idx >> 9;
    int l = row & (LL-1);
    int lo = l-12; if(lo<0) lo=0;
    int hi = l+12; if(hi>LL-1) hi=LL-1;
    float cf = (float)(hi-lo+1) * (1.f/25.f);
    float wcol[7], bias;
    if(f32){
        const float* w = (const float*)wv;
        #pragma unroll
        for(int i=0;i<7;i++) wcol[i] = w[i*DD + d];
        bias = ((const float*)bv)[d];
    }else{
        const bf16* w = (const bf16*)wv;
        #pragma unroll
        for(int i=0;i<7;i++) wcol[i] = b2f(w[i*DD + d]);
        bias = b2f(((const bf16*)bv)[d]);
    }
    float sa = 0.f, ta = 0.f;
    #pragma unroll
    for(int i=0;i<7;i++){
        sa += xs[row*7+i]*wcol[i];
        ta += xm[row*7+i]*wcol[i];
    }
    seas[idx] = f2b(sa + bias*(1.f-cf));
    float t = ta + bias*cf;
    if(accumulate) t += b2f(trend[idx]);
    trend[idx] = f2b(t);
}

// trig table Tg[t][k]: k=2(f-1) -> cos(2*pi*f*t/1024), k=2(f-1)+1 -> sin, f=1..32
__global__ __launch_bounds__(64) void trig_init(bf16* __restrict__ Tg){
    int t = blockIdx.x, k = threadIdx.x;
    int f = (k >> 1) + 1;
    int ph = (f*t) & 1023;
    float s, c;
    __sincosf((float)ph * (6.28318530717958647692f/1024.f), &s, &c);
    Tg[(size_t)t*GK + k] = f2b((k & 1) ? s : c);
}

// twiddle Tw[k][j]: k=2(f-1) -> cos(2*pi*f*j/64), k=2(f-1)+1 -> -sin(...), f=1..32
__global__ __launch_bounds__(64) void tw_init(bf16* __restrict__ Tw){
    int j = threadIdx.x, k = blockIdx.x;
    int f = (k >> 1) + 1;
    int ph = (f*j) & 63;
    float s, c;
    __sincosf((float)ph * (6.28318530717958647692f/64.f), &s, &c);
    Tw[(size_t)k*64 + j] = f2b((k & 1) ? -s : c);
}

// MFMA DFT: rows = (b,l,h) flattened [65536 x 64], Tw [64 comps x 64 j].
// qhat/khat via 2 MFMAs each; C_f = qf*conj(kf) via lane^1 re/im pairing;
// cross-head mean subtract via lane^16 pairing; Ab[(b*MM+h*LL+l)*64 + c].
__global__ __launch_bounds__(256) void dft2(const bf16* __restrict__ qg,
                                            const bf16* __restrict__ kg,
                                            const bf16* __restrict__ Tw,
                                            bf16* __restrict__ Ab,
                                            int same_qk){
    int tid = threadIdx.x, wv = tid >> 6, lane = tid & 63;
    int qd = lane >> 4, n = lane & 15;
    int m0 = blockIdx.x*64 + wv*16;     // wave's 16 global rows (= 2 l x 8 h)
    const short* qp = (const short*)qg;
    const short* kp = (const short*)kg;
    const short* tw = (const short*)Tw;
    short8 aq0 = *(const short8*)&qp[(size_t)(m0+n)*64 + qd*8];
    short8 aq1 = *(const short8*)&qp[(size_t)(m0+n)*64 + 32 + qd*8];
    short8 bw[4][2];
    #pragma unroll
    for(int nt=0;nt<4;nt++){
        bw[nt][0] = *(const short8*)&tw[(size_t)(nt*16+n)*64 + qd*8];
        bw[nt][1] = *(const short8*)&tw[(size_t)(nt*16+n)*64 + 32 + qd*8];
    }
    floatx4 dq[4], dk[4];
    #pragma unroll
    for(int nt=0;nt<4;nt++){
        floatx4 a = {};
        a = __builtin_amdgcn_mfma_f32_16x16x32_bf16(aq0, bw[nt][0], a, 0,0,0);
        a = __builtin_amdgcn_mfma_f32_16x16x32_bf16(aq1, bw[nt][1], a, 0,0,0);
        dq[nt] = a;
    }
    if(same_qk){
        #pragma unroll
        for(int nt=0;nt<4;nt++) dk[nt] = dq[nt];
    }else{
        short8 ak0 = *(const short8*)&kp[(size_t)(m0+n)*64 + qd*8];
        short8 ak1 = *(const short8*)&kp[(size_t)(m0+n)*64 + 32 + qd*8];
        #pragma unroll
        for(int nt=0;nt<4;nt++){
            floatx4 a = {};
            a = __builtin_amdgcn_mfma_f32_16x16x32_bf16(ak0, bw[nt][0], a, 0,0,0);
            a = __builtin_amdgcn_mfma_f32_16x16x32_bf16(ak1, bw[nt][1], a, 0,0,0);
            dk[nt] = a;
        }
    }
    // even c lanes hold re, odd c lanes hold im (c = nt*16+n).
    #pragma unroll
    for(int nt=0;nt<4;nt++){
        float o[4];
        #pragma unroll
        for(int r=0;r<4;r++){
            float a  = dq[nt][r], pa = __shfl_xor(a, 1);
            float c  = dk[nt][r], pc = __shfl_xor(c, 1);
            // even: re = qre*kre + qim*kim; odd: stored -im = qre*kim - qim*kre
            o[r] = (n & 1) ? (pa*c - a*pc) : (a*c + pa*pc);
        }
        float s = o[0]+o[1]+o[2]+o[3];
        s += __shfl_xor(s, 16);          // pair qd<->qd^1: all 8 h of same l
        float mean = s*0.125f;
        #pragma unroll
        for(int r=0;r<4;r++){
            int row = m0 + qd*4 + r;
            int b = row >> 13, l = (row >> 3) & (LL-1), hh = row & 7;
            Ab[((size_t)b*MM + (size_t)hh*LL + l)*GK + nt*16 + n] =
                f2b((o[r]-mean)*(1.f/512.f));
        }
    }
}

// Row sums S_m = sum_t exp(corr[m][t]) (no max subtract: |corr|<~0.2, exp safe).
// grid (512 m-tiles, 4 t-quarters, BB); partial sums via atomicAdd (rs zeroed).
__global__ __launch_bounds__(256) void rowstats2(const bf16* __restrict__ Ab,
                                                 const bf16* __restrict__ Tg,
                                                 float* __restrict__ rs){
    __shared__ float red[4][16];
    int tid = threadIdx.x, wv = tid >> 6, lane = tid & 63;
    int q = lane >> 4, n = lane & 15;
    int m0 = blockIdx.x*16, bloc = blockIdx.z;
    int t0 = blockIdx.y*256 + wv*64;
    const short* Abase = (const short*)(Ab + ((size_t)bloc*MM)*GK);
    const short* Tb = (const short*)Tg;
    short8 af0 = *(const short8*)&Abase[(size_t)(m0+n)*GK + q*8];
    short8 af1 = *(const short8*)&Abase[(size_t)(m0+n)*GK + 32 + q*8];
    float s[4] = {};
    #pragma unroll
    for(int nt=0;nt<4;nt++){
        short8 b0 = *(const short8*)&Tb[(size_t)(t0+nt*16+n)*GK + q*8];
        short8 b1 = *(const short8*)&Tb[(size_t)(t0+nt*16+n)*GK + 32 + q*8];
        floatx4 a = {};
        a = __builtin_amdgcn_mfma_f32_16x16x32_bf16(af0, b0, a, 0,0,0);
        a = __builtin_amdgcn_mfma_f32_16x16x32_bf16(af1, b1, a, 0,0,0);
        #pragma unroll
        for(int r=0;r<4;r++) s[r] += __expf(a[r]);
    }
    #pragma unroll
    for(int o=1;o<16;o<<=1)
        #pragma unroll
        for(int r=0;r<4;r++) s[r] += __shfl_xor(s[r], o, 64);
    if(n == 0){
        #pragma unroll
        for(int r=0;r<4;r++) red[wv][q*4+r] = s[r];
    }
    __syncthreads();
    if(tid < 16)
        atomicAdd(&rs[(size_t)bloc*MM + m0 + tid],
                  red[0][tid]+red[1][tid]+red[2][tid]+red[3][tid]);
}

// Fused corr-recompute + softmax + PV, 512 threads (8 waves, 16 waves/CU).
// P wave-private in LDS (no barrier on the P round-trip); invS folded into Vs.
// Out[i,c] -> dst[b][c*8192 + h*1024 + i].
__global__ __launch_bounds__(512, 4) void fused_pv(const bf16* __restrict__ Ab,
                                                   const bf16* __restrict__ Tg,
                                                   const float* __restrict__ rs,
                                                   const bf16* __restrict__ v,
                                                   bf16* __restrict__ dst){
    __shared__ __align__(16) unsigned short Pl[128][68];  // [i_loc][j_loc], wave-private rows
    __shared__ __align__(16) unsigned short Vs[64][68];   // [c][j_loc], pre-scaled by invS_j
    __shared__ float st[LL];                              // invS per j
    int tid = threadIdx.x, wv = tid >> 6, lane = tid & 63;
    int q = lane >> 4, n = lane & 15;
    int i0 = blockIdx.x * 128;
    int h = blockIdx.y, bloc = blockIdx.z;
    const short* Abase = (const short*)(Ab + ((size_t)bloc*MM + (size_t)h*LL)*GK);
    const short* Tb = (const short*)Tg;
    const float* rsb = rs + (size_t)bloc*MM + (size_t)h*LL;
    const unsigned short* vbase = (const unsigned short*)(v + (size_t)bloc*LL*DD + h*DH);
    for(int s=tid; s<LL; s+=512) st[s] = 1.f / rsb[s];
    short8 tgf[2];
    tgf[0] = *(const short8*)&Tb[(size_t)(i0 + wv*16 + n)*GK + q*8];
    tgf[1] = *(const short8*)&Tb[(size_t)(i0 + wv*16 + n)*GK + 32 + q*8];
    int cv = tid & 63, jg = tid >> 6;    // V staging: c, j-group (8 groups)
    floatx4 acc[4] = {};
    for(int j0=0; j0<LL; j0+=64){
        __syncthreads();                 // protect Vs/st from previous readers
        #pragma unroll
        for(int p=0;p<4;p++){
            int j = (jg*4+p)*2;
            unsigned short v0 = vbase[(size_t)(j0+j)*DD + cv];
            unsigned short v1 = vbase[(size_t)(j0+j+1)*DD + cv];
            float s0 = bu2f(v0)*st[j0+j], s1 = bu2f(v1)*st[j0+j+1];
            *(unsigned*)&Vs[cv][j] = (unsigned)f2bu(s0) | ((unsigned)f2bu(s1) << 16);
        }
        __syncthreads();
        // MFMA1 + exp + wave-private P write (lane holds 4 consecutive j at one i)
        #pragma unroll
        for(int tj=0;tj<4;tj++){
            short8 a0 = *(const short8*)&Abase[(size_t)(j0+tj*16+n)*GK + q*8];
            short8 a1 = *(const short8*)&Abase[(size_t)(j0+tj*16+n)*GK + 32 + q*8];
            floatx4 d = {};
            d = __builtin_amdgcn_mfma_f32_16x16x32_bf16(a0, tgf[0], d, 0,0,0);
            d = __builtin_amdgcn_mfma_f32_16x16x32_bf16(a1, tgf[1], d, 0,0,0);
            ushort4v pk;
            pk.x = f2bu(__expf(d[0]));
            pk.y = f2bu(__expf(d[1]));
            pk.z = f2bu(__expf(d[2]));
            pk.w = f2bu(__expf(d[3]));
            *(ushort4v*)&Pl[wv*16 + n][tj*16 + q*4] = pk;
        }
        // MFMA2: Out[i][c] += P[i][j] * Vs[c][j]  (P rows wave-private -> no barrier)
        #pragma unroll
        for(int kc=0;kc<2;kc++){
            union { ushort4v h2[2]; short8 s; } a2, b2v;
            const unsigned short* pp = &Pl[wv*16 + n][kc*32 + q*8];
            a2.h2[0] = *(const ushort4v*)pp;
            a2.h2[1] = *(const ushort4v*)(pp+4);
            #pragma unroll
            for(int cs=0;cs<4;cs++){
                const unsigned short* vp = &Vs[cs*16 + n][kc*32 + q*8];
                b2v.h2[0] = *(const ushort4v*)vp;
                b2v.h2[1] = *(const ushort4v*)(vp+4);
                acc[cs] = __builtin_amdgcn_mfma_f32_16x16x32_bf16(a2.s, b2v.s, acc[cs], 0,0,0);
            }
        }
    }
    bf16* db = dst + (size_t)bloc*LL*DD;
    #pragma unroll
    for(int cs=0;cs<4;cs++){
        int c = cs*16 + n;
        int ib = i0 + wv*16 + q*4;
        ushort4v pk;
        pk.x = f2bu(acc[cs][0]);
        pk.y = f2bu(acc[cs][1]);
        pk.z = f2bu(acc[cs][2]);
        pk.w = f2bu(acc[cs][3]);
        *(ushort4v*)(db + (size_t)c*MM + h*LL + ib) = pk;
    }
}

// out = (seas + trend_sum) @ proj_w + proj_b  (dtype per flag)
__global__ __launch_bounds__(64) void final_kernel(const bf16* __restrict__ s,
                                                   const bf16* __restrict__ t,
                                                   const void* __restrict__ pwv,
                                                   const void* __restrict__ pbv,
                                                   const int* __restrict__ flag,
                                                   void* __restrict__ outv){
    bool f32 = (*flag != 0);
    int row = blockIdx.x;
    int lane = threadIdx.x;
    const bf16* sr = s + (size_t)row*DD;
    const bf16* tr = t + (size_t)row*DD;
    float acc[CO] = {};
    for(int j=lane; j<DD; j+=64){
        float dv = b2f(sr[j]) + b2f(tr[j]);
        if(f32){
            const float* pw = (const float*)pwv;
            #pragma unroll
            for(int c=0;c<CO;c++) acc[c] += dv * pw[j*CO + c];
        }else{
            const bf16* pw = (const bf16*)pwv;
            #pragma unroll
            for(int c=0;c<CO;c++) acc[c] += dv * b2f(pw[j*CO + c]);
        }
    }
    #pragma unroll
    for(int c=0;c<CO;c++){
        float vsum = acc[c];
        for(int off=32;off;off>>=1) vsum += __shfl_down(vsum,off,64);
        if(lane==0){
            float bias = f32 ? ((const float*)pbv)[c] : b2f(((const bf16*)pbv)[c]);
            float o = vsum + bias;
            if(f32) ((float*)outv)[(size_t)row*CO + c] = o;
            else    ((bf16*)outv)[(size_t)row*CO + c] = f2b(o);
        }
    }
}

extern "C" void kernel_launch(void* const* d_in, const int* in_sizes, int n_in,
                              void* d_out, int out_size, void* d_ws, size_t ws_size,
                              hipStream_t stream){
    const void* x_enc  = d_in[0];
    const void* x_dec  = d_in[2];
    const void* enc_w  = d_in[4];
    const void* enc_b  = d_in[5];
    const void* dec_w  = d_in[6];
    const void* dec_b  = d_in[7];
    const void* proj_w = d_in[8];
    const void* proj_b = d_in[9];

    int*  flag = (int*)d_ws;
    const size_t NE = (size_t)BB*LL*DD;
    bf16* A  = (bf16*)((char*)d_ws + 1024);
    bf16* Bf = A  + NE;
    bf16* C  = Bf + NE;
    bf16* T  = C  + NE;
    bf16* Tg = T  + NE;                              // [1024][64]
    bf16* Tw = Tg + (size_t)LL*GK;                   // [64][64]
    float* xs = (float*)(Tw + 64*64);
    float* xm = xs + (size_t)BB*LL*7;
    bf16* Ab  = (bf16*)(xm + (size_t)BB*LL*7);       // [BB][MM][GK]
    float* rs = (float*)(Ab + (size_t)BB*MM*GK);     // [BB][MM]

    sniff_kernel<<<1,64,0,stream>>>((const unsigned*)x_enc, flag);
    trig_init<<<LL,64,0,stream>>>(Tg);
    tw_init<<<64,64,0,stream>>>(Tw);

    auto autocorr = [&](const bf16* q, const bf16* kv, bf16* dst){
        hipMemsetAsync(rs, 0, (size_t)BB*MM*sizeof(float), stream);
        dft2<<<1024, 256, 0, stream>>>(q, kv, Tw, Ab, (q==kv) ? 1 : 0);
        rowstats2<<<dim3(512,4,BB), 256, 0, stream>>>(Ab, Tg, rs);
        fused_pv<<<dim3(8, NH, BB), 512, 0, stream>>>(Ab, Tg, rs, kv, dst);
    };

    const int MA_GRID = (BB*LL*7 + 255)/256;
    ma7_kernel<<<MA_GRID,256,0,stream>>>(x_enc, flag, xs, xm);
    embed2_kernel<<<16384,256,0,stream>>>(xs, xm, enc_w, enc_b, flag, A, T, 0);
    autocorr(A, A, Bf);      // layer 1 -> Bf
    autocorr(Bf, Bf, A);     // layer 2 -> A (= enc_seasonal out)

    ma7_kernel<<<MA_GRID,256,0,stream>>>(x_dec, flag, xs, xm);
    embed2_kernel<<<16384,256,0,stream>>>(xs, xm, dec_w, dec_b, flag, Bf, T, 1);
    autocorr(Bf, A, C);      // cross layer -> C

    final_kernel<<<BB*LL,64,0,stream>>>(C, T, proj_w, proj_b, flag, d_out);
}

// Round 9
// 420.481 us; speedup vs baseline: 1.6354x; 1.3664x over previous
//
#include <hip/hip_runtime.h>
#include <hip/hip_bf16.h>

#define BB 8
#define LL 1024
#define DD 512
#define NH 8
#define DH 64
#define CO 7
#define GK 64          // K for corr GEMM: f=1..32, (re,im) pairs; f=0 dropped (softmax-invariant)
#define MM 8192        // NH*LL rows per batch

typedef __hip_bfloat16 bf16;
typedef __attribute__((ext_vector_type(8))) short short8;
typedef __attribute__((ext_vector_type(4))) float floatx4;
typedef __attribute__((ext_vector_type(4))) unsigned short ushort4v;

__device__ __forceinline__ float b2f(bf16 v){ return __bfloat162float(v); }
__device__ __forceinline__ bf16 f2b(float v){ return __float2bfloat16(v); }
__device__ __forceinline__ unsigned short f2bu(float v){
    bf16 h = f2b(v); return *(unsigned short*)&h;
}
__device__ __forceinline__ float bu2f(unsigned short u){
    union{unsigned i; float f;} x; x.i = ((unsigned)u)<<16; return x.f;
}

// Decide whether global float data is genuine f32 (flag=1) or packed bf16 (flag=0).
__global__ void sniff_kernel(const unsigned* __restrict__ x, int* __restrict__ flag){
    unsigned u = x[threadIdx.x];
    int e = (u >> 23) & 0xff;
    int sane = (e >= 32 && e <= 200) ? 1 : 0;
    unsigned long long m = __ballot(sane);
    if(threadIdx.x == 0) *flag = (__popcll(m) >= 32) ? 1 : 0;
}

// moving average over the 7-channel input: xm = MA25(x), xs = x - xm  (f32 out)
__global__ __launch_bounds__(256) void ma7_kernel(const void* __restrict__ xv,
                                                  const int* __restrict__ flag,
                                                  float* __restrict__ xs,
                                                  float* __restrict__ xm){
    int idx = blockIdx.x*256 + threadIdx.x;
    if(idx >= BB*LL*7) return;
    bool f32 = (*flag != 0);
    int i = idx % 7;
    int row = idx / 7;
    int l = row & (LL-1);
    int b = row >> 10;
    int lo = l-12; if(lo<0) lo=0;
    int hi = l+12; if(hi>LL-1) hi=LL-1;
    float s = 0.f, xc;
    if(f32){
        const float* x = (const float*)xv + ((size_t)b*LL)*7 + i;
        for(int m=lo;m<=hi;m++) s += x[(size_t)m*7];
        xc = x[(size_t)l*7];
    }else{
        const bf16* x = (const bf16*)xv + ((size_t)b*LL)*7 + i;
        for(int m=lo;m<=hi;m++) s += b2f(x[(size_t)m*7]);
        xc = b2f(x[(size_t)l*7]);
    }
    float ma = s*(1.f/25.f);
    xm[idx] = ma;
    xs[idx] = xc - ma;
}

// seas[b,l,d] = xs@W + bias*(1-cnt/25); trend = xm@W + bias*cnt/25 (+= if accumulate)
__global__ __launch_bounds__(256) void embed2_kernel(const float* __restrict__ xs,
                                                     const float* __restrict__ xm,
                                                     const void* __restrict__ wv,
                                                     const void* __restrict__ bv,
                                                     const int* __restrict__ flag,
                                                     bf16* __restrict__ seas,
                                                     bf16* __restrict__ trend,
                                                     int accumulate){
    bool f32 = (*flag != 0);
    int idx = blockIdx.x*256 + threadIdx.x;
    int d = idx & (DD-1);
    int row = idx >> 9;
    int l = row & (LL-1);
    int lo = l-12; if(lo<0) lo=0;
    int hi = l+12; if(hi>LL-1) hi=LL-1;
    float cf = (float)(hi-lo+1) * (1.f/25.f);
    float wcol[7], bias;
    if(f32){
        const float* w = (const float*)wv;
        #pragma unroll
        for(int i=0;i<7;i++) wcol[i] = w[i*DD + d];
        bias = ((const float*)bv)[d];
    }else{
        const bf16* w = (const bf16*)wv;
        #pragma unroll
        for(int i=0;i<7;i++) wcol[i] = b2f(w[i*DD + d]);
        bias = b2f(((const bf16*)bv)[d]);
    }
    float sa = 0.f, ta = 0.f;
    #pragma unroll
    for(int i=0;i<7;i++){
        sa += xs[row*7+i]*wcol[i];
        ta += xm[row*7+i]*wcol[i];
    }
    seas[idx] = f2b(sa + bias*(1.f-cf));
    float t = ta + bias*cf;
    if(accumulate) t += b2f(trend[idx]);
    trend[idx] = f2b(t);
}

// trig table Tg[t][k]: k=2(f-1) -> cos(2*pi*f*t/1024), k=2(f-1)+1 -> sin, f=1..32
__global__ __launch_bounds__(64) void trig_init(bf16* __restrict__ Tg){
    int t = blockIdx.x, k = threadIdx.x;
    int f = (k >> 1) + 1;
    int ph = (f*t) & 1023;
    float s, c;
    __sincosf((float)ph * (6.28318530717958647692f/1024.f), &s, &c);
    Tg[(size_t)t*GK + k] = f2b((k & 1) ? s : c);
}

// twiddle Tw[k][j]: k=2(f-1) -> cos(2*pi*f*j/64), k=2(f-1)+1 -> -sin(...), f=1..32
__global__ __launch_bounds__(64) void tw_init(bf16* __restrict__ Tw){
    int j = threadIdx.x, k = blockIdx.x;
    int f = (k >> 1) + 1;
    int ph = (f*j) & 63;
    float s, c;
    __sincosf((float)ph * (6.28318530717958647692f/64.f), &s, &c);
    Tw[(size_t)k*64 + j] = f2b((k & 1) ? -s : c);
}

// MFMA DFT: rows = (b,l,h) flattened [65536 x 64], Tw [64 comps x 64 j].
__global__ __launch_bounds__(256) void dft2(const bf16* __restrict__ qg,
                                            const bf16* __restrict__ kg,
                                            const bf16* __restrict__ Tw,
                                            bf16* __restrict__ Ab,
                                            int same_qk){
    int tid = threadIdx.x, wv = tid >> 6, lane = tid & 63;
    int qd = lane >> 4, n = lane & 15;
    int m0 = blockIdx.x*64 + wv*16;     // wave's 16 global rows (= 2 l x 8 h)
    const short* qp = (const short*)qg;
    const short* kp = (const short*)kg;
    const short* tw = (const short*)Tw;
    short8 aq0 = *(const short8*)&qp[(size_t)(m0+n)*64 + qd*8];
    short8 aq1 = *(const short8*)&qp[(size_t)(m0+n)*64 + 32 + qd*8];
    short8 bw[4][2];
    #pragma unroll
    for(int nt=0;nt<4;nt++){
        bw[nt][0] = *(const short8*)&tw[(size_t)(nt*16+n)*64 + qd*8];
        bw[nt][1] = *(const short8*)&tw[(size_t)(nt*16+n)*64 + 32 + qd*8];
    }
    floatx4 dq[4], dk[4];
    #pragma unroll
    for(int nt=0;nt<4;nt++){
        floatx4 a = {};
        a = __builtin_amdgcn_mfma_f32_16x16x32_bf16(aq0, bw[nt][0], a, 0,0,0);
        a = __builtin_amdgcn_mfma_f32_16x16x32_bf16(aq1, bw[nt][1], a, 0,0,0);
        dq[nt] = a;
    }
    if(same_qk){
        #pragma unroll
        for(int nt=0;nt<4;nt++) dk[nt] = dq[nt];
    }else{
        short8 ak0 = *(const short8*)&kp[(size_t)(m0+n)*64 + qd*8];
        short8 ak1 = *(const short8*)&kp[(size_t)(m0+n)*64 + 32 + qd*8];
        #pragma unroll
        for(int nt=0;nt<4;nt++){
            floatx4 a = {};
            a = __builtin_amdgcn_mfma_f32_16x16x32_bf16(ak0, bw[nt][0], a, 0,0,0);
            a = __builtin_amdgcn_mfma_f32_16x16x32_bf16(ak1, bw[nt][1], a, 0,0,0);
            dk[nt] = a;
        }
    }
    #pragma unroll
    for(int nt=0;nt<4;nt++){
        float o[4];
        #pragma unroll
        for(int r=0;r<4;r++){
            float a  = dq[nt][r], pa = __shfl_xor(a, 1);
            float c  = dk[nt][r], pc = __shfl_xor(c, 1);
            o[r] = (n & 1) ? (pa*c - a*pc) : (a*c + pa*pc);
        }
        float s = o[0]+o[1]+o[2]+o[3];
        s += __shfl_xor(s, 16);          // pair qd<->qd^1: all 8 h of same l
        float mean = s*0.125f;
        #pragma unroll
        for(int r=0;r<4;r++){
            int row = m0 + qd*4 + r;
            int b = row >> 13, l = (row >> 3) & (LL-1), hh = row & 7;
            Ab[((size_t)b*MM + (size_t)hh*LL + l)*GK + nt*16 + n] =
                f2b((o[r]-mean)*(1.f/512.f));
        }
    }
}

// Row sums S_m = sum_t exp(corr[m][t]) (no max subtract: |corr|<~0.2, exp safe).
// Block = 64 m x ALL 1024 t (wave = t-quarter). A-frags loaded once, reused over
// 16 nt-groups -> load:MFMA 1:3.2. Direct store, no atomics.
__global__ __launch_bounds__(256) void rowstats3(const bf16* __restrict__ Ab,
                                                 const bf16* __restrict__ Tg,
                                                 float* __restrict__ rs){
    __shared__ float red[4][64];
    int tid = threadIdx.x, wv = tid >> 6, lane = tid & 63;
    int q = lane >> 4, n = lane & 15;
    int m0 = blockIdx.x*64, bloc = blockIdx.y;
    const short* Abase = (const short*)(Ab + ((size_t)bloc*MM)*GK);
    const short* Tb = (const short*)Tg;
    short8 af[4][2];
    #pragma unroll
    for(int mg=0;mg<4;mg++){
        af[mg][0] = *(const short8*)&Abase[(size_t)(m0+mg*16+n)*GK + q*8];
        af[mg][1] = *(const short8*)&Abase[(size_t)(m0+mg*16+n)*GK + 32 + q*8];
    }
    float s[4][4] = {};
    #pragma unroll
    for(int nt=0;nt<16;nt++){
        int t = wv*256 + nt*16 + n;
        short8 b0 = *(const short8*)&Tb[(size_t)t*GK + q*8];
        short8 b1 = *(const short8*)&Tb[(size_t)t*GK + 32 + q*8];
        #pragma unroll
        for(int mg=0;mg<4;mg++){
            floatx4 d = {};
            d = __builtin_amdgcn_mfma_f32_16x16x32_bf16(af[mg][0], b0, d, 0,0,0);
            d = __builtin_amdgcn_mfma_f32_16x16x32_bf16(af[mg][1], b1, d, 0,0,0);
            #pragma unroll
            for(int r=0;r<4;r++) s[mg][r] += __expf(d[r]);
        }
    }
    #pragma unroll
    for(int o=1;o<16;o<<=1)
        #pragma unroll
        for(int mg=0;mg<4;mg++)
            #pragma unroll
            for(int r=0;r<4;r++) s[mg][r] += __shfl_xor(s[mg][r], o, 64);
    if(n == 0){
        #pragma unroll
        for(int mg=0;mg<4;mg++)
            #pragma unroll
            for(int r=0;r<4;r++) red[wv][mg*16 + q*4 + r] = s[mg][r];
    }
    __syncthreads();
    if(tid < 64)
        rs[(size_t)bloc*MM + m0 + tid] = red[0][tid]+red[1][tid]+red[2][tid]+red[3][tid];
}

// Fused corr-recompute + softmax + PV, 512 threads (8 waves).
// P wave-private in LDS; invS folded into Vs. Out[i,c] -> dst[b][c*8192+h*1024+i].
__global__ __launch_bounds__(512, 4) void fused_pv(const bf16* __restrict__ Ab,
                                                   const bf16* __restrict__ Tg,
                                                   const float* __restrict__ rs,
                                                   const bf16* __restrict__ v,
                                                   bf16* __restrict__ dst){
    __shared__ __align__(16) unsigned short Pl[128][68];  // [i_loc][j_loc], wave-private rows
    __shared__ __align__(16) unsigned short Vs[64][68];   // [c][j_loc], pre-scaled by invS_j
    __shared__ float st[LL];                              // invS per j
    int tid = threadIdx.x, wv = tid >> 6, lane = tid & 63;
    int q = lane >> 4, n = lane & 15;
    int i0 = blockIdx.x * 128;
    int h = blockIdx.y, bloc = blockIdx.z;
    const short* Abase = (const short*)(Ab + ((size_t)bloc*MM + (size_t)h*LL)*GK);
    const short* Tb = (const short*)Tg;
    const float* rsb = rs + (size_t)bloc*MM + (size_t)h*LL;
    const unsigned short* vbase = (const unsigned short*)(v + (size_t)bloc*LL*DD + h*DH);
    for(int s=tid; s<LL; s+=512) st[s] = 1.f / rsb[s];
    short8 tgf[2];
    tgf[0] = *(const short8*)&Tb[(size_t)(i0 + wv*16 + n)*GK + q*8];
    tgf[1] = *(const short8*)&Tb[(size_t)(i0 + wv*16 + n)*GK + 32 + q*8];
    int cv = tid & 63, jg = tid >> 6;
    floatx4 acc[4] = {};
    for(int j0=0; j0<LL; j0+=64){
        __syncthreads();
        #pragma unroll
        for(int p=0;p<4;p++){
            int j = (jg*4+p)*2;
            unsigned short v0 = vbase[(size_t)(j0+j)*DD + cv];
            unsigned short v1 = vbase[(size_t)(j0+j+1)*DD + cv];
            float s0 = bu2f(v0)*st[j0+j], s1 = bu2f(v1)*st[j0+j+1];
            *(unsigned*)&Vs[cv][j] = (unsigned)f2bu(s0) | ((unsigned)f2bu(s1) << 16);
        }
        __syncthreads();
        #pragma unroll
        for(int tj=0;tj<4;tj++){
            short8 a0 = *(const short8*)&Abase[(size_t)(j0+tj*16+n)*GK + q*8];
            short8 a1 = *(const short8*)&Abase[(size_t)(j0+tj*16+n)*GK + 32 + q*8];
            floatx4 d = {};
            d = __builtin_amdgcn_mfma_f32_16x16x32_bf16(a0, tgf[0], d, 0,0,0);
            d = __builtin_amdgcn_mfma_f32_16x16x32_bf16(a1, tgf[1], d, 0,0,0);
            ushort4v pk;
            pk.x = f2bu(__expf(d[0]));
            pk.y = f2bu(__expf(d[1]));
            pk.z = f2bu(__expf(d[2]));
            pk.w = f2bu(__expf(d[3]));
            *(ushort4v*)&Pl[wv*16 + n][tj*16 + q*4] = pk;
        }
        #pragma unroll
        for(int kc=0;kc<2;kc++){
            union { ushort4v h2[2]; short8 s; } a2, b2v;
            const unsigned short* pp = &Pl[wv*16 + n][kc*32 + q*8];
            a2.h2[0] = *(const ushort4v*)pp;
            a2.h2[1] = *(const ushort4v*)(pp+4);
            #pragma unroll
            for(int cs=0;cs<4;cs++){
                const unsigned short* vp = &Vs[cs*16 + n][kc*32 + q*8];
                b2v.h2[0] = *(const ushort4v*)vp;
                b2v.h2[1] = *(const ushort4v*)(vp+4);
                acc[cs] = __builtin_amdgcn_mfma_f32_16x16x32_bf16(a2.s, b2v.s, acc[cs], 0,0,0);
            }
        }
    }
    bf16* db = dst + (size_t)bloc*LL*DD;
    #pragma unroll
    for(int cs=0;cs<4;cs++){
        int c = cs*16 + n;
        int ib = i0 + wv*16 + q*4;
        ushort4v pk;
        pk.x = f2bu(acc[cs][0]);
        pk.y = f2bu(acc[cs][1]);
        pk.z = f2bu(acc[cs][2]);
        pk.w = f2bu(acc[cs][3]);
        *(ushort4v*)(db + (size_t)c*MM + h*LL + ib) = pk;
    }
}

// out = (seas + trend_sum) @ proj_w + proj_b  (dtype per flag)
__global__ __launch_bounds__(64) void final_kernel(const bf16* __restrict__ s,
                                                   const bf16* __restrict__ t,
                                                   const void* __restrict__ pwv,
                                                   const void* __restrict__ pbv,
                                                   const int* __restrict__ flag,
                                                   void* __restrict__ outv){
    bool f32 = (*flag != 0);
    int row = blockIdx.x;
    int lane = threadIdx.x;
    const bf16* sr = s + (size_t)row*DD;
    const bf16* tr = t + (size_t)row*DD;
    float acc[CO] = {};
    for(int j=lane; j<DD; j+=64){
        float dv = b2f(sr[j]) + b2f(tr[j]);
        if(f32){
            const float* pw = (const float*)pwv;
            #pragma unroll
            for(int c=0;c<CO;c++) acc[c] += dv * pw[j*CO + c];
        }else{
            const bf16* pw = (const bf16*)pwv;
            #pragma unroll
            for(int c=0;c<CO;c++) acc[c] += dv * b2f(pw[j*CO + c]);
        }
    }
    #pragma unroll
    for(int c=0;c<CO;c++){
        float vsum = acc[c];
        for(int off=32;off;off>>=1) vsum += __shfl_down(vsum,off,64);
        if(lane==0){
            float bias = f32 ? ((const float*)pbv)[c] : b2f(((const bf16*)pbv)[c]);
            float o = vsum + bias;
            if(f32) ((float*)outv)[(size_t)row*CO + c] = o;
            else    ((bf16*)outv)[(size_t)row*CO + c] = f2b(o);
        }
    }
}

extern "C" void kernel_launch(void* const* d_in, const int* in_sizes, int n_in,
                              void* d_out, int out_size, void* d_ws, size_t ws_size,
                              hipStream_t stream){
    const void* x_enc  = d_in[0];
    const void* x_dec  = d_in[2];
    const void* enc_w  = d_in[4];
    const void* enc_b  = d_in[5];
    const void* dec_w  = d_in[6];
    const void* dec_b  = d_in[7];
    const void* proj_w = d_in[8];
    const void* proj_b = d_in[9];

    int*  flag = (int*)d_ws;
    const size_t NE = (size_t)BB*LL*DD;
    bf16* A  = (bf16*)((char*)d_ws + 1024);
    bf16* Bf = A  + NE;
    bf16* C  = Bf + NE;
    bf16* T  = C  + NE;
    bf16* Tg = T  + NE;                              // [1024][64]
    bf16* Tw = Tg + (size_t)LL*GK;                   // [64][64]
    float* xs = (float*)(Tw + 64*64);
    float* xm = xs + (size_t)BB*LL*7;
    bf16* Ab  = (bf16*)(xm + (size_t)BB*LL*7);       // [BB][MM][GK]
    float* rs = (float*)(Ab + (size_t)BB*MM*GK);     // [BB][MM]

    sniff_kernel<<<1,64,0,stream>>>((const unsigned*)x_enc, flag);
    trig_init<<<LL,64,0,stream>>>(Tg);
    tw_init<<<64,64,0,stream>>>(Tw);

    auto autocorr = [&](const bf16* q, const bf16* kv, bf16* dst){
        dft2<<<1024, 256, 0, stream>>>(q, kv, Tw, Ab, (q==kv) ? 1 : 0);
        rowstats3<<<dim3(128, BB), 256, 0, stream>>>(Ab, Tg, rs);
        fused_pv<<<dim3(8, NH, BB), 512, 0, stream>>>(Ab, Tg, rs, kv, dst);
    };

    const int MA_GRID = (BB*LL*7 + 255)/256;
    ma7_kernel<<<MA_GRID,256,0,stream>>>(x_enc, flag, xs, xm);
    embed2_kernel<<<16384,256,0,stream>>>(xs, xm, enc_w, enc_b, flag, A, T, 0);
    autocorr(A, A, Bf);      // layer 1 -> Bf
    autocorr(Bf, Bf, A);     // layer 2 -> A (= enc_seasonal out)

    ma7_kernel<<<MA_GRID,256,0,stream>>>(x_dec, flag, xs, xm);
    embed2_kernel<<<16384,256,0,stream>>>(xs, xm, dec_w, dec_b, flag, Bf, T, 1);
    autocorr(Bf, A, C);      // cross layer -> C

    final_kernel<<<BB*LL,64,0,stream>>>(C, T, proj_w, proj_b, flag, d_out);
}